// Round 13
// baseline (1027.294 us; speedup 1.0000x reference)
//
#include <hip/hip_runtime.h>
#include <cstdint>
#include <cstddef>

#define NE   1024    // N_EMBD
#define DF   4096    // D_FF
#define KACT 1024    // K_ACTIVE
#define NTOK 16384   // B*S

typedef _Float16       f16x8  __attribute__((ext_vector_type(8)));
typedef unsigned short u16x8  __attribute__((ext_vector_type(8)));
typedef float          f32x4  __attribute__((ext_vector_type(4)));
typedef float          f32x16 __attribute__((ext_vector_type(16)));

#define MFMA16(a,b,c) __builtin_amdgcn_mfma_f32_16x16x32_f16(a,b,c,0,0,0)
#define MFMA32(a,b,c) __builtin_amdgcn_mfma_f32_32x32x16_f16(a,b,c,0,0,0)

// async global->LDS, 16B per lane; LDS dest = uniform base + lane*16 (linear)
#define GLD16(gp, lp) __builtin_amdgcn_global_load_lds( \
    (const __attribute__((address_space(1))) unsigned int*)(gp), \
    (__attribute__((address_space(3))) unsigned int*)(lp), 16, 0, 0)

// LDS tiles are [rows][32] f16 (64 B rows, 4x 16B chunks). Chunk-slot XOR
// involution sigma_r = ((r>>1)^(r>>3))&3.  r12 post-mortem: the old
// ((r>>1)&3) was conflict-free for the 16x16 read pattern (16 rows x 4
// chunks) but 4-way aliased the 32x32 pattern (32 consecutive rows at one
// chunk: rows r, r+8, r+16, r+24 shared a bank cluster -> 5e7 conflicts).
// Adding row bit 3 breaks the mod-8 alias; <=2-way under any lane grouping.
// global_load_lds fills linearly; the same involution pre-swizzles the
// per-lane GLOBAL source chunk (both-sides-or-neither, rule 21).
__device__ __forceinline__ int sigma(int row) {
    return ((row >> 1) ^ (row >> 3)) & 3;
}
__device__ __forceinline__ int swz(int row, int lk) {
    return row * 32 + ((((lk) >> 3) ^ sigma(row)) << 3);
}

// split fp32 -> hi fp16 + lo fp16 (residual)
__device__ __forceinline__ void cvt8(const float* f, f16x8& h, f16x8& l) {
    #pragma unroll
    for (int j = 0; j < 8; ++j) {
        _Float16 hh = (_Float16)f[j];
        h[j] = hh;
        l[j] = (_Float16)(f[j] - (float)hh);
    }
}

// ---------------------------------------------------------------------------
// Fused prep (1 launch): Wg->gh, Wu->uh, Wd->wdh (fp16), x->xh+xl (split).
// ---------------------------------------------------------------------------
__global__ __launch_bounds__(256) void k_prep(
    const float* __restrict__ Wg, const float* __restrict__ Wu,
    const float* __restrict__ Wd, const float* __restrict__ x,
    _Float16* __restrict__ gh, _Float16* __restrict__ uh,
    _Float16* __restrict__ wdh, _Float16* __restrict__ xh,
    _Float16* __restrict__ xl, int nw8, int nx8)
{
    int i = blockIdx.x * 256 + threadIdx.x;
    const float* s; _Float16* dh; _Float16* dl = nullptr; int j;
    if (i < nw8)            { s = Wg; dh = gh;  j = i; }
    else if (i < 2*nw8)     { s = Wu; dh = uh;  j = i - nw8; }
    else if (i < 3*nw8)     { s = Wd; dh = wdh; j = i - 2*nw8; }
    else if (i < 3*nw8+nx8) { s = x;  dh = xh;  dl = xl; j = i - 3*nw8; }
    else return;
    float4 a = ((const float4*)s)[2*j], b = ((const float4*)s)[2*j+1];
    float f[8] = {a.x,a.y,a.z,a.w,b.x,b.y,b.z,b.w};
    if (dl) {
        f16x8 hh, ll; cvt8(f, hh, ll);
        ((f16x8*)dh)[j] = hh; ((f16x8*)dl)[j] = ll;
    } else {
        f16x8 hh;
        #pragma unroll
        for (int q = 0; q < 8; ++q) hh[q] = (_Float16)f[q];
        ((f16x8*)dh)[j] = hh;
    }
}

// ---------------------------------------------------------------------------
// Up-projection via fp16x2 MFMA on 32x32x16 (2495 TF ceiling, -17% issue).
//   acc = xh*W + xl*W (x split h+l, weights single fp16 — r11-verified).
// BM=128 tokens, BN=64 ff, BK=32. 4 waves (2x2); per-wave 64x32 (g and u).
// LDS per buf: XH/XL [128][32], GH/UH [64][32] = 24KB; x2 = 48KB.
// A-frag: row=lane&31, k=(lane>>5)*8+e. C/D: col=lane&31,
// row=(reg&3)+8*(reg>>2)+4*(lane>>5)  [r12-verified: absmax matched 16x16].
// ---------------------------------------------------------------------------
#define OXH 0
#define OXL (128*32)
#define OGH (2*128*32)
#define OUH (2*128*32 + 64*32)
#define GUBUF (2*128*32 + 2*64*32)   // 12288 elements = 24KB

__global__ __launch_bounds__(256) void k_gemm_gu_mfma(
    const _Float16* __restrict__ xh, const _Float16* __restrict__ xl,
    const _Float16* __restrict__ gh, const _Float16* __restrict__ uh,
    _Float16* __restrict__ z, int nM)
{
    __shared__ _Float16 L[2 * GUBUF];
    const int t = threadIdx.x, lane = t & 63, wid = t >> 6;

    // 4x4 supertile swizzle for L2 locality
    int bid = blockIdx.x, mi, ni;
    if ((nM & 3) == 0) {
        int st = bid >> 4, lo = bid & 15, nstM = nM >> 2;
        mi = ((st % nstM) << 2) + (lo & 3);
        ni = ((st / nstM) << 2) + (lo >> 2);
    } else { mi = bid % nM; ni = bid / nM; }
    const int m0 = mi * 128, f0 = ni * 64;

    // ---- staging roles (per lane): linear LDS fill, pre-swizzled source ----
    const int rr = lane >> 2, slot = lane & 3;
    size_t xoff[2];
    #pragma unroll
    for (int q = 0; q < 2; ++q) {
        int row = wid*32 + q*16 + rr;
        int ss  = slot ^ sigma(row);
        xoff[q] = (size_t)(m0 + row) * (NE*2) + ss*16;
    }
    size_t woff;   // wave w stages GH and UH rows [w*16, w*16+16)
    {
        int row = wid*16 + rr;
        int ss  = slot ^ sigma(row);
        woff = (size_t)(f0 + row) * (NE*2) + ss*16;
    }
    const char* xhB = (const char*)xh;
    const char* xlB = (const char*)xl;
    const char* ghB = (const char*)gh;
    const char* uhB = (const char*)uh;

    const int wr = wid >> 1, wc = wid & 1;
    const int l31 = lane & 31, lks = (lane >> 5) * 8;   // 32x32 frag coords

    f32x16 accg[2] = {}, accu[2] = {};

    // stage K-step kt into buffer b (6 GLD16/lane)
    #define GU_STAGE(b, kt) do {                                              \
        _Float16* Lb = L + (b) * GUBUF;                                       \
        const size_t ka = (size_t)(kt) * 64;                                  \
        const char* xhK = xhB + ka;  const char* xlK = xlB + ka;              \
        const char* ghK = ghB + ka;  const char* uhK = uhB + ka;              \
        _Pragma("unroll")                                                     \
        for (int q = 0; q < 2; ++q) {                                         \
            GLD16(xhK + xoff[q], Lb + OXH + (wid*32 + q*16)*32);              \
            GLD16(xlK + xoff[q], Lb + OXL + (wid*32 + q*16)*32);              \
        }                                                                     \
        GLD16(ghK + woff, Lb + OGH + (wid*16)*32);                            \
        GLD16(uhK + woff, Lb + OUH + (wid*16)*32);                            \
    } while (0)

    GU_STAGE(0, 0);
    __syncthreads();

    int buf = 0;
    for (int kt = 0; kt < 32; ++kt) {
        if (kt + 1 < 32) GU_STAGE(buf ^ 1, kt + 1);
        const _Float16* Lb = &L[buf * GUBUF];
        f16x8 ah[2][2], al[2][2];   // [ksub][Mtile]
        #pragma unroll
        for (int s = 0; s < 2; ++s)
            #pragma unroll
            for (int mt = 0; mt < 2; ++mt) {
                int off = swz(wr*64 + mt*32 + l31, s*16 + lks);
                ah[s][mt] = *(const f16x8*)&Lb[OXH + off];
                al[s][mt] = *(const f16x8*)&Lb[OXL + off];
            }
        #pragma unroll
        for (int s = 0; s < 2; ++s) {
            int offb = swz(wc*32 + l31, s*16 + lks);
            f16x8 bg = *(const f16x8*)&Lb[OGH + offb];
            f16x8 bu = *(const f16x8*)&Lb[OUH + offb];
            #pragma unroll
            for (int mt = 0; mt < 2; ++mt) {
                accg[mt] = MFMA32(ah[s][mt], bg, accg[mt]);
                accg[mt] = MFMA32(al[s][mt], bg, accg[mt]);
                accu[mt] = MFMA32(ah[s][mt], bu, accu[mt]);
                accu[mt] = MFMA32(al[s][mt], bu, accu[mt]);
            }
        }
        __syncthreads();
        buf ^= 1;
    }

    // epilogue: silu(g)*u with native exp; 32x32 C-layout store
    #pragma unroll
    for (int mt = 0; mt < 2; ++mt)
        #pragma unroll
        for (int r = 0; r < 16; ++r) {
            int row = m0 + wr*64 + mt*32 + (r & 3) + 8*(r >> 2) + 4*(lane >> 5);
            int col = f0 + wc*32 + l31;
            float g = accg[mt][r], u = accu[mt][r];
            float sg = g / (1.0f + __expf(-g));
            z[(size_t)row*DF + col] = (_Float16)(sg * u);
        }
    #undef GU_STAGE
}

// ---------------------------------------------------------------------------
// Exact per-token top-K mask on fp16 z: 2-pass radix select on the 15-bit
// magnitude key; stable ties by ascending index. Masks in place. (r10-verified)
// ---------------------------------------------------------------------------
__global__ __launch_bounds__(256) void k_topk_mask16(_Float16* __restrict__ z)
{
    __shared__ unsigned short zrow[DF];
    __shared__ unsigned hist[256];
    __shared__ int      cnts[256];
    __shared__ unsigned s_b1;
    __shared__ unsigned s_tkey;
    __shared__ int      s_remaining;

    const int t = threadIdx.x;
    unsigned short* zp = (unsigned short*)(z + (size_t)blockIdx.x * DF);

    for (int i = t; i < DF/8; i += 256) {
        ((ushort4*)zrow)[2*i]   = ((const ushort4*)zp)[2*i];
        ((ushort4*)zrow)[2*i+1] = ((const ushort4*)zp)[2*i+1];
    }
    if (t == 0) s_remaining = KACT;
    __syncthreads();

    hist[t] = 0u;
    __syncthreads();
    {
        const int base = t * 16;
        #pragma unroll
        for (int j = 0; j < 16; ++j) {
            unsigned key = zrow[base + j] & 0x7FFFu;
            atomicAdd(&hist[key >> 7], 1u);
        }
    }
    __syncthreads();
    if (t == 0) {
        int rem = s_remaining;
        int b = 255;
        for (; b > 0; --b) {
            int c = (int)hist[b];
            if (rem - c <= 0) break;
            rem -= c;
        }
        s_b1 = (unsigned)b;
        s_remaining = rem;
    }
    __syncthreads();

    const unsigned b1 = s_b1;
    hist[t] = 0u;
    __syncthreads();
    {
        const int base = t * 16;
        #pragma unroll
        for (int j = 0; j < 16; ++j) {
            unsigned key = zrow[base + j] & 0x7FFFu;
            if ((key >> 7) == b1) atomicAdd(&hist[key & 0x7Fu], 1u);
        }
    }
    __syncthreads();
    if (t == 0) {
        int rem = s_remaining;
        int b = 127;
        for (; b > 0; --b) {
            int c = (int)hist[b];
            if (rem - c <= 0) break;
            rem -= c;
        }
        s_tkey = (b1 << 7) | (unsigned)b;
        s_remaining = rem;
    }
    __syncthreads();

    const unsigned tkey = s_tkey;
    const int      E    = s_remaining;

    const int base = t * 16;
    int cnt = 0;
    #pragma unroll
    for (int j = 0; j < 16; ++j)
        if ((zrow[base + j] & 0x7FFFu) == tkey) cnt++;
    cnts[t] = cnt;
    __syncthreads();
    if (t == 0) {
        int run = 0;
        for (int i = 0; i < 256; ++i) { int c = cnts[i]; cnts[i] = run; run += c; }
    }
    __syncthreads();

    int rank = cnts[t];
    #pragma unroll
    for (int q = 0; q < 2; ++q) {
        u16x8 v;
        #pragma unroll
        for (int j = 0; j < 8; ++j) {
            int f = base + q*8 + j;
            unsigned short raw = zrow[f];
            unsigned key = raw & 0x7FFFu;
            bool sel;
            if (key > tkey)       sel = true;
            else if (key == tkey) { sel = (rank < E); rank++; }
            else                  sel = false;
            v[j] = sel ? raw : (unsigned short)0;
        }
        *(u16x8*)(zp + base + q*8) = v;
    }
}

// ---------------------------------------------------------------------------
// Down-projection, single fp16 16x16x32 MFMA, global_load_lds staged.
// (r11-verified structure; swizzle updated to sigma' — still <=2-way/free
// for the 16x16 read pattern.)
// ---------------------------------------------------------------------------
#define OZH 0
#define OWH (128*32)
#define DNBUF (2*128*32)   // 8192 elements = 16KB

__global__ __launch_bounds__(256) void k_gemm_down_mfma(
    const _Float16* __restrict__ z, const _Float16* __restrict__ wdh,
    float* __restrict__ out, int tok0, int nM)
{
    __shared__ _Float16 L[2 * DNBUF];
    const int t = threadIdx.x, lane = t & 63, wid = t >> 6;

    int bid = blockIdx.x, mi, ni;
    if ((nM & 3) == 0) {
        int st = bid >> 4, lo = bid & 15, nstM = nM >> 2;
        mi = ((st % nstM) << 2) + (lo & 3);
        ni = ((st / nstM) << 2) + (lo >> 2);
    } else { mi = bid % nM; ni = bid / nM; }
    const int m0 = mi * 128, d0 = ni * 128;

    const int rr = lane >> 2, slot = lane & 3;
    size_t zoff[2], wof[2];
    #pragma unroll
    for (int q = 0; q < 2; ++q) {
        int row = wid*32 + q*16 + rr;
        int ss  = slot ^ sigma(row);
        zoff[q] = (size_t)(m0 + row) * (DF*2) + ss*16;
        wof[q]  = (size_t)(d0 + row) * (DF*2) + ss*16;
    }
    const char* zB = (const char*)z;
    const char* wB = (const char*)wdh;

    const int wr = wid >> 1, wc = wid & 1;
    const int lrow = lane & 15, lk = (lane >> 4) * 8;

    f32x4 acc[4][4] = {};

    #define DN_STAGE(b, kt) do {                                              \
        _Float16* Lb = L + (b) * DNBUF;                                       \
        size_t ka = (size_t)(kt) * 64;                                        \
        _Pragma("unroll")                                                     \
        for (int q = 0; q < 2; ++q) {                                         \
            GLD16(zB + zoff[q] + ka, Lb + OZH + (wid*32 + q*16)*32);          \
            GLD16(wB + wof[q]  + ka, Lb + OWH + (wid*32 + q*16)*32);          \
        }                                                                     \
    } while (0)

    DN_STAGE(0, 0);
    __syncthreads();

    int buf = 0;
    for (int kt = 0; kt < DF/32; ++kt) {
        if (kt + 1 < DF/32) DN_STAGE(buf ^ 1, kt + 1);
        const _Float16* Lb = &L[buf * DNBUF];
        f16x8 ah[4], bh[4];
        #pragma unroll
        for (int mf = 0; mf < 4; ++mf)
            ah[mf] = *(const f16x8*)&Lb[OZH + swz(wr*64 + mf*16 + lrow, lk)];
        #pragma unroll
        for (int nf = 0; nf < 4; ++nf)
            bh[nf] = *(const f16x8*)&Lb[OWH + swz(wc*64 + nf*16 + lrow, lk)];
        #pragma unroll
        for (int nf = 0; nf < 4; ++nf)
            #pragma unroll
            for (int mf = 0; mf < 4; ++mf)
                acc[mf][nf] = MFMA16(ah[mf], bh[nf], acc[mf][nf]);
        __syncthreads();
        buf ^= 1;
    }

    #pragma unroll
    for (int mf = 0; mf < 4; ++mf)
        #pragma unroll
        for (int nf = 0; nf < 4; ++nf)
            #pragma unroll
            for (int r = 0; r < 4; ++r) {
                int row = tok0 + m0 + wr*64 + mf*16 + (lane>>4)*4 + r;
                int col = d0 + wc*64 + nf*16 + lrow;
                out[(size_t)row*NE + col] = acc[mf][nf][r];
            }
    #undef DN_STAGE
}

// ---------------------------------------------------------------------------
extern "C" void kernel_launch(void* const* d_in, const int* in_sizes, int n_in,
                              void* d_out, int out_size, void* d_ws, size_t ws_size,
                              hipStream_t stream)
{
    const float* x  = (const float*)d_in[0];
    const float* Wg = (const float*)d_in[1];
    const float* Wu = (const float*)d_in[2];
    const float* Wd = (const float*)d_in[3];
    float* out = (float*)d_out;

    // fixed-size weights: gh/uh (DF*NE f16) + wdh (NE*DF f16) = 3 arrays
    const size_t wElems = (size_t)DF * NE;
    const size_t fixedBytes = wElems * 2 * 3;   // 25 MB

    // chunk tokens: need z fp16 (CT*DF*2) + xh/xl (CT*NE*2 each) + fixed
    int CT = NTOK;
    while (CT > 128 &&
           (size_t)CT*DF*2 + (size_t)CT*NE*4 + fixedBytes > ws_size) CT >>= 1;

    char* wsb = (char*)d_ws;
    _Float16* zbuf = (_Float16*)wsb;
    _Float16* xh   = (_Float16*)(wsb + (size_t)CT*DF*2);
    _Float16* xl   = xh + (size_t)CT*NE;
    _Float16* gh   = xl + (size_t)CT*NE;
    _Float16* uh   = gh + wElems;
    _Float16* wdh  = uh + wElems;

    const int nw8 = (int)(wElems / 8);

    for (int tok0 = 0; tok0 < NTOK; tok0 += CT) {
        int nM  = CT / 128;
        int nx8 = CT * NE / 8;
        int nPrep = 3*nw8 + nx8;
        k_prep<<<dim3((nPrep+255)/256), 256, 0, stream>>>(
            Wg, Wu, Wd, x + (size_t)tok0*NE, gh, uh, wdh, xh, xl, nw8, nx8);
        k_gemm_gu_mfma  <<<dim3(nM * (DF/64)),  256, 0, stream>>>(xh, xl, gh, uh, zbuf, nM);
        k_topk_mask16   <<<dim3(CT),            256, 0, stream>>>(zbuf);
        k_gemm_down_mfma<<<dim3(nM * (NE/128)), 256, 0, stream>>>(zbuf, wdh, out, tok0, nM);
    }
}

// Round 14
// 984.024 us; speedup vs baseline: 1.0440x; 1.0440x over previous
//
#include <hip/hip_runtime.h>
#include <cstdint>
#include <cstddef>

#define NE   1024    // N_EMBD
#define DF   4096    // D_FF
#define KACT 1024    // K_ACTIVE
#define NTOK 16384   // B*S

typedef _Float16       f16x8  __attribute__((ext_vector_type(8)));
typedef unsigned short u16x8  __attribute__((ext_vector_type(8)));
typedef float          f32x4  __attribute__((ext_vector_type(4)));
typedef float          f32x16 __attribute__((ext_vector_type(16)));

#define MFMA16(a,b,c) __builtin_amdgcn_mfma_f32_16x16x32_f16(a,b,c,0,0,0)
#define MFMA32(a,b,c) __builtin_amdgcn_mfma_f32_32x32x16_f16(a,b,c,0,0,0)

// async global->LDS, 16B per lane; LDS dest = uniform base + lane*16 (linear)
#define GLD16(gp, lp) __builtin_amdgcn_global_load_lds( \
    (const __attribute__((address_space(1))) unsigned int*)(gp), \
    (__attribute__((address_space(3))) unsigned int*)(lp), 16, 0, 0)

// LDS tiles are [rows][32] f16 (64 B rows, 4x 16B chunks = bank-groups).
// r13 post-mortem: conflict count was INVARIANT under sigma change -> LDS
// pairs lane i with lane i+32; the 32x32 frag puts those lanes at chunks
// differing in bit0 -> groups g,g^1 collide quad-wise under any row-uniform
// sigma whose bit1 is quad-constant. Fix: sigma_gu bit1 toggles every 2 rows
// (separates paired lanes into different group-pairs), bit0 spreads stride-2
// rows. Verified by hand: all 8-lane phases hit 8 distinct groups under BOTH
// (i,i+32)-quad and consecutive-8 pairings, for s=0 and s=1.
__device__ __forceinline__ int sigma_gu(int row) {
    return (((row >> 1) & 1) << 1) | ((row >> 2) & 1);
}
__device__ __forceinline__ int swz_gu(int row, int lk) {
    return row * 32 + ((((lk) >> 3) ^ sigma_gu(row)) << 3);
}
// down-GEMM (16x16 pattern): r11-proven sigma, measured 0 conflicts.
__device__ __forceinline__ int sigma_dn(int row) {
    return (row >> 1) & 3;
}
__device__ __forceinline__ int swz_dn(int row, int lk) {
    return row * 32 + ((((lk) >> 3) ^ sigma_dn(row)) << 3);
}

// split fp32 -> hi fp16 + lo fp16 (residual)
__device__ __forceinline__ void cvt8(const float* f, f16x8& h, f16x8& l) {
    #pragma unroll
    for (int j = 0; j < 8; ++j) {
        _Float16 hh = (_Float16)f[j];
        h[j] = hh;
        l[j] = (_Float16)(f[j] - (float)hh);
    }
}

// ---------------------------------------------------------------------------
// Fused prep (1 launch): Wg->gh, Wu->uh, Wd->wdh (fp16), x->xh+xl (split).
// ---------------------------------------------------------------------------
__global__ __launch_bounds__(256) void k_prep(
    const float* __restrict__ Wg, const float* __restrict__ Wu,
    const float* __restrict__ Wd, const float* __restrict__ x,
    _Float16* __restrict__ gh, _Float16* __restrict__ uh,
    _Float16* __restrict__ wdh, _Float16* __restrict__ xh,
    _Float16* __restrict__ xl, int nw8, int nx8)
{
    int i = blockIdx.x * 256 + threadIdx.x;
    const float* s; _Float16* dh; _Float16* dl = nullptr; int j;
    if (i < nw8)            { s = Wg; dh = gh;  j = i; }
    else if (i < 2*nw8)     { s = Wu; dh = uh;  j = i - nw8; }
    else if (i < 3*nw8)     { s = Wd; dh = wdh; j = i - 2*nw8; }
    else if (i < 3*nw8+nx8) { s = x;  dh = xh;  dl = xl; j = i - 3*nw8; }
    else return;
    float4 a = ((const float4*)s)[2*j], b = ((const float4*)s)[2*j+1];
    float f[8] = {a.x,a.y,a.z,a.w,b.x,b.y,b.z,b.w};
    if (dl) {
        f16x8 hh, ll; cvt8(f, hh, ll);
        ((f16x8*)dh)[j] = hh; ((f16x8*)dl)[j] = ll;
    } else {
        f16x8 hh;
        #pragma unroll
        for (int q = 0; q < 8; ++q) hh[q] = (_Float16)f[q];
        ((f16x8*)dh)[j] = hh;
    }
}

// ---------------------------------------------------------------------------
// Up-projection via fp16x2 MFMA on 32x32x16 (2495 TF ceiling).
//   acc = xh*W + xl*W (x split h+l, weights single fp16 — r11-verified).
// BM=128 tokens, BN=64 ff, BK=32. 4 waves (2x2); per-wave 64x32 (g and u).
// LDS per buf: XH/XL [128][32], GH/UH [64][32] = 24KB; x2 = 48KB.
// A-frag: row=lane&31, k=(lane>>5)*8+e. C/D: col=lane&31,
// row=(reg&3)+8*(reg>>2)+4*(lane>>5)  [r12-verified: absmax matched 16x16].
// Read offsets hoisted out of the K-loop (loop-invariant; r13 VALU fix).
// ---------------------------------------------------------------------------
#define OXH 0
#define OXL (128*32)
#define OGH (2*128*32)
#define OUH (2*128*32 + 64*32)
#define GUBUF (2*128*32 + 2*64*32)   // 12288 elements = 24KB

__global__ __launch_bounds__(256) void k_gemm_gu_mfma(
    const _Float16* __restrict__ xh, const _Float16* __restrict__ xl,
    const _Float16* __restrict__ gh, const _Float16* __restrict__ uh,
    _Float16* __restrict__ z, int nM)
{
    __shared__ _Float16 L[2 * GUBUF];
    const int t = threadIdx.x, lane = t & 63, wid = t >> 6;

    // 4x4 supertile swizzle for L2 locality
    int bid = blockIdx.x, mi, ni;
    if ((nM & 3) == 0) {
        int st = bid >> 4, lo = bid & 15, nstM = nM >> 2;
        mi = ((st % nstM) << 2) + (lo & 3);
        ni = ((st / nstM) << 2) + (lo >> 2);
    } else { mi = bid % nM; ni = bid / nM; }
    const int m0 = mi * 128, f0 = ni * 64;

    // ---- staging roles (per lane): linear LDS fill, pre-swizzled source ----
    const int rr = lane >> 2, slot = lane & 3;
    size_t xoff[2];
    #pragma unroll
    for (int q = 0; q < 2; ++q) {
        int row = wid*32 + q*16 + rr;
        int ss  = slot ^ sigma_gu(row);
        xoff[q] = (size_t)(m0 + row) * (NE*2) + ss*16;
    }
    size_t woff;   // wave w stages GH and UH rows [w*16, w*16+16)
    {
        int row = wid*16 + rr;
        int ss  = slot ^ sigma_gu(row);
        woff = (size_t)(f0 + row) * (NE*2) + ss*16;
    }
    const char* xhB = (const char*)xh;
    const char* xlB = (const char*)xl;
    const char* ghB = (const char*)gh;
    const char* uhB = (const char*)uh;

    const int wr = wid >> 1, wc = wid & 1;
    const int l31 = lane & 31, lks = (lane >> 5) * 8;   // 32x32 frag coords

    // hoisted, loop-invariant LDS read offsets
    int aoff[2][2], boff[2];
    #pragma unroll
    for (int s = 0; s < 2; ++s) {
        #pragma unroll
        for (int mt = 0; mt < 2; ++mt)
            aoff[s][mt] = swz_gu(wr*64 + mt*32 + l31, s*16 + lks);
        boff[s] = swz_gu(wc*32 + l31, s*16 + lks);
    }

    f32x16 accg[2] = {}, accu[2] = {};

    // stage K-step kt into buffer b (6 GLD16/lane)
    #define GU_STAGE(b, kt) do {                                              \
        _Float16* Lb = L + (b) * GUBUF;                                       \
        const size_t ka = (size_t)(kt) * 64;                                  \
        const char* xhK = xhB + ka;  const char* xlK = xlB + ka;              \
        const char* ghK = ghB + ka;  const char* uhK = uhB + ka;              \
        _Pragma("unroll")                                                     \
        for (int q = 0; q < 2; ++q) {                                         \
            GLD16(xhK + xoff[q], Lb + OXH + (wid*32 + q*16)*32);              \
            GLD16(xlK + xoff[q], Lb + OXL + (wid*32 + q*16)*32);              \
        }                                                                     \
        GLD16(ghK + woff, Lb + OGH + (wid*16)*32);                            \
        GLD16(uhK + woff, Lb + OUH + (wid*16)*32);                            \
    } while (0)

    GU_STAGE(0, 0);
    __syncthreads();

    int buf = 0;
    for (int kt = 0; kt < 32; ++kt) {
        if (kt + 1 < 32) GU_STAGE(buf ^ 1, kt + 1);
        const _Float16* Lb = &L[buf * GUBUF];
        f16x8 ah[2][2], al[2][2];   // [ksub][Mtile]
        #pragma unroll
        for (int s = 0; s < 2; ++s)
            #pragma unroll
            for (int mt = 0; mt < 2; ++mt) {
                ah[s][mt] = *(const f16x8*)&Lb[OXH + aoff[s][mt]];
                al[s][mt] = *(const f16x8*)&Lb[OXL + aoff[s][mt]];
            }
        #pragma unroll
        for (int s = 0; s < 2; ++s) {
            f16x8 bg = *(const f16x8*)&Lb[OGH + boff[s]];
            f16x8 bu = *(const f16x8*)&Lb[OUH + boff[s]];
            #pragma unroll
            for (int mt = 0; mt < 2; ++mt) {
                accg[mt] = MFMA32(ah[s][mt], bg, accg[mt]);
                accg[mt] = MFMA32(al[s][mt], bg, accg[mt]);
                accu[mt] = MFMA32(ah[s][mt], bu, accu[mt]);
                accu[mt] = MFMA32(al[s][mt], bu, accu[mt]);
            }
        }
        __syncthreads();
        buf ^= 1;
    }

    // epilogue: silu(g)*u with native exp; 32x32 C-layout store
    #pragma unroll
    for (int mt = 0; mt < 2; ++mt)
        #pragma unroll
        for (int r = 0; r < 16; ++r) {
            int row = m0 + wr*64 + mt*32 + (r & 3) + 8*(r >> 2) + 4*(lane >> 5);
            int col = f0 + wc*32 + l31;
            float g = accg[mt][r], u = accu[mt][r];
            float sg = g / (1.0f + __expf(-g));
            z[(size_t)row*DF + col] = (_Float16)(sg * u);
        }
    #undef GU_STAGE
}

// ---------------------------------------------------------------------------
// Exact per-token top-K mask on fp16 z: 2-pass radix select on the 15-bit
// magnitude key; stable ties by ascending index. Masks in place. (r10-verified)
// ---------------------------------------------------------------------------
__global__ __launch_bounds__(256) void k_topk_mask16(_Float16* __restrict__ z)
{
    __shared__ unsigned short zrow[DF];
    __shared__ unsigned hist[256];
    __shared__ int      cnts[256];
    __shared__ unsigned s_b1;
    __shared__ unsigned s_tkey;
    __shared__ int      s_remaining;

    const int t = threadIdx.x;
    unsigned short* zp = (unsigned short*)(z + (size_t)blockIdx.x * DF);

    for (int i = t; i < DF/8; i += 256) {
        ((ushort4*)zrow)[2*i]   = ((const ushort4*)zp)[2*i];
        ((ushort4*)zrow)[2*i+1] = ((const ushort4*)zp)[2*i+1];
    }
    if (t == 0) s_remaining = KACT;
    __syncthreads();

    hist[t] = 0u;
    __syncthreads();
    {
        const int base = t * 16;
        #pragma unroll
        for (int j = 0; j < 16; ++j) {
            unsigned key = zrow[base + j] & 0x7FFFu;
            atomicAdd(&hist[key >> 7], 1u);
        }
    }
    __syncthreads();
    if (t == 0) {
        int rem = s_remaining;
        int b = 255;
        for (; b > 0; --b) {
            int c = (int)hist[b];
            if (rem - c <= 0) break;
            rem -= c;
        }
        s_b1 = (unsigned)b;
        s_remaining = rem;
    }
    __syncthreads();

    const unsigned b1 = s_b1;
    hist[t] = 0u;
    __syncthreads();
    {
        const int base = t * 16;
        #pragma unroll
        for (int j = 0; j < 16; ++j) {
            unsigned key = zrow[base + j] & 0x7FFFu;
            if ((key >> 7) == b1) atomicAdd(&hist[key & 0x7Fu], 1u);
        }
    }
    __syncthreads();
    if (t == 0) {
        int rem = s_remaining;
        int b = 127;
        for (; b > 0; --b) {
            int c = (int)hist[b];
            if (rem - c <= 0) break;
            rem -= c;
        }
        s_tkey = (b1 << 7) | (unsigned)b;
        s_remaining = rem;
    }
    __syncthreads();

    const unsigned tkey = s_tkey;
    const int      E    = s_remaining;

    const int base = t * 16;
    int cnt = 0;
    #pragma unroll
    for (int j = 0; j < 16; ++j)
        if ((zrow[base + j] & 0x7FFFu) == tkey) cnt++;
    cnts[t] = cnt;
    __syncthreads();
    if (t == 0) {
        int run = 0;
        for (int i = 0; i < 256; ++i) { int c = cnts[i]; cnts[i] = run; run += c; }
    }
    __syncthreads();

    int rank = cnts[t];
    #pragma unroll
    for (int q = 0; q < 2; ++q) {
        u16x8 v;
        #pragma unroll
        for (int j = 0; j < 8; ++j) {
            int f = base + q*8 + j;
            unsigned short raw = zrow[f];
            unsigned key = raw & 0x7FFFu;
            bool sel;
            if (key > tkey)       sel = true;
            else if (key == tkey) { sel = (rank < E); rank++; }
            else                  sel = false;
            v[j] = sel ? raw : (unsigned short)0;
        }
        *(u16x8*)(zp + base + q*8) = v;
    }
}

// ---------------------------------------------------------------------------
// Down-projection, single fp16 16x16x32 MFMA, global_load_lds staged.
// (r11-verified structure and sigma_dn — measured 0 conflicts there.)
// ---------------------------------------------------------------------------
#define OZH 0
#define OWH (128*32)
#define DNBUF (2*128*32)   // 8192 elements = 16KB

__global__ __launch_bounds__(256) void k_gemm_down_mfma(
    const _Float16* __restrict__ z, const _Float16* __restrict__ wdh,
    float* __restrict__ out, int tok0, int nM)
{
    __shared__ _Float16 L[2 * DNBUF];
    const int t = threadIdx.x, lane = t & 63, wid = t >> 6;

    int bid = blockIdx.x, mi, ni;
    if ((nM & 3) == 0) {
        int st = bid >> 4, lo = bid & 15, nstM = nM >> 2;
        mi = ((st % nstM) << 2) + (lo & 3);
        ni = ((st / nstM) << 2) + (lo >> 2);
    } else { mi = bid % nM; ni = bid / nM; }
    const int m0 = mi * 128, d0 = ni * 128;

    const int rr = lane >> 2, slot = lane & 3;
    size_t zoff[2], wof[2];
    #pragma unroll
    for (int q = 0; q < 2; ++q) {
        int row = wid*32 + q*16 + rr;
        int ss  = slot ^ sigma_dn(row);
        zoff[q] = (size_t)(m0 + row) * (DF*2) + ss*16;
        wof[q]  = (size_t)(d0 + row) * (DF*2) + ss*16;
    }
    const char* zB = (const char*)z;
    const char* wB = (const char*)wdh;

    const int wr = wid >> 1, wc = wid & 1;
    const int lrow = lane & 15, lk = (lane >> 4) * 8;

    // hoisted loop-invariant read offsets
    int aoff[4], boff[4];
    #pragma unroll
    for (int mf = 0; mf < 4; ++mf)
        aoff[mf] = swz_dn(wr*64 + mf*16 + lrow, lk);
    #pragma unroll
    for (int nf = 0; nf < 4; ++nf)
        boff[nf] = swz_dn(wc*64 + nf*16 + lrow, lk);

    f32x4 acc[4][4] = {};

    #define DN_STAGE(b, kt) do {                                              \
        _Float16* Lb = L + (b) * DNBUF;                                       \
        size_t ka = (size_t)(kt) * 64;                                        \
        _Pragma("unroll")                                                     \
        for (int q = 0; q < 2; ++q) {                                         \
            GLD16(zB + zoff[q] + ka, Lb + OZH + (wid*32 + q*16)*32);          \
            GLD16(wB + wof[q]  + ka, Lb + OWH + (wid*32 + q*16)*32);          \
        }                                                                     \
    } while (0)

    DN_STAGE(0, 0);
    __syncthreads();

    int buf = 0;
    for (int kt = 0; kt < DF/32; ++kt) {
        if (kt + 1 < DF/32) DN_STAGE(buf ^ 1, kt + 1);
        const _Float16* Lb = &L[buf * DNBUF];
        f16x8 ah[4], bh[4];
        #pragma unroll
        for (int mf = 0; mf < 4; ++mf)
            ah[mf] = *(const f16x8*)&Lb[OZH + aoff[mf]];
        #pragma unroll
        for (int nf = 0; nf < 4; ++nf)
            bh[nf] = *(const f16x8*)&Lb[OWH + boff[nf]];
        #pragma unroll
        for (int nf = 0; nf < 4; ++nf)
            #pragma unroll
            for (int mf = 0; mf < 4; ++mf)
                acc[mf][nf] = MFMA16(ah[mf], bh[nf], acc[mf][nf]);
        __syncthreads();
        buf ^= 1;
    }

    #pragma unroll
    for (int mf = 0; mf < 4; ++mf)
        #pragma unroll
        for (int nf = 0; nf < 4; ++nf)
            #pragma unroll
            for (int r = 0; r < 4; ++r) {
                int row = tok0 + m0 + wr*64 + mf*16 + (lane>>4)*4 + r;
                int col = d0 + wc*64 + nf*16 + lrow;
                out[(size_t)row*NE + col] = acc[mf][nf][r];
            }
    #undef DN_STAGE
}

// ---------------------------------------------------------------------------
extern "C" void kernel_launch(void* const* d_in, const int* in_sizes, int n_in,
                              void* d_out, int out_size, void* d_ws, size_t ws_size,
                              hipStream_t stream)
{
    const float* x  = (const float*)d_in[0];
    const float* Wg = (const float*)d_in[1];
    const float* Wu = (const float*)d_in[2];
    const float* Wd = (const float*)d_in[3];
    float* out = (float*)d_out;

    // fixed-size weights: gh/uh (DF*NE f16) + wdh (NE*DF f16) = 3 arrays
    const size_t wElems = (size_t)DF * NE;
    const size_t fixedBytes = wElems * 2 * 3;   // 25 MB

    // chunk tokens: need z fp16 (CT*DF*2) + xh/xl (CT*NE*2 each) + fixed
    int CT = NTOK;
    while (CT > 128 &&
           (size_t)CT*DF*2 + (size_t)CT*NE*4 + fixedBytes > ws_size) CT >>= 1;

    char* wsb = (char*)d_ws;
    _Float16* zbuf = (_Float16*)wsb;
    _Float16* xh   = (_Float16*)(wsb + (size_t)CT*DF*2);
    _Float16* xl   = xh + (size_t)CT*NE;
    _Float16* gh   = xl + (size_t)CT*NE;
    _Float16* uh   = gh + wElems;
    _Float16* wdh  = uh + wElems;

    const int nw8 = (int)(wElems / 8);

    for (int tok0 = 0; tok0 < NTOK; tok0 += CT) {
        int nM  = CT / 128;
        int nx8 = CT * NE / 8;
        int nPrep = 3*nw8 + nx8;
        k_prep<<<dim3((nPrep+255)/256), 256, 0, stream>>>(
            Wg, Wu, Wd, x + (size_t)tok0*NE, gh, uh, wdh, xh, xl, nw8, nx8);
        k_gemm_gu_mfma  <<<dim3(nM * (DF/64)),  256, 0, stream>>>(xh, xl, gh, uh, zbuf, nM);
        k_topk_mask16   <<<dim3(CT),            256, 0, stream>>>(zbuf);
        k_gemm_down_mfma<<<dim3(nM * (NE/128)), 256, 0, stream>>>(zbuf, wdh, out, tok0, nM);
    }
}

// Round 15
// 929.174 us; speedup vs baseline: 1.1056x; 1.0590x over previous
//
#include <hip/hip_runtime.h>
#include <cstdint>
#include <cstddef>

#define NE   1024    // N_EMBD
#define DF   4096    // D_FF
#define KACT 1024    // K_ACTIVE
#define NTOK 16384   // B*S

typedef _Float16       f16x8  __attribute__((ext_vector_type(8)));
typedef unsigned short u16x8  __attribute__((ext_vector_type(8)));
typedef float          f32x4  __attribute__((ext_vector_type(4)));
typedef float          f32x16 __attribute__((ext_vector_type(16)));

#define MFMA16(a,b,c) __builtin_amdgcn_mfma_f32_16x16x32_f16(a,b,c,0,0,0)
#define MFMA32(a,b,c) __builtin_amdgcn_mfma_f32_32x32x16_f16(a,b,c,0,0,0)

// async global->LDS, 16B per lane; LDS dest = uniform base + lane*16 (linear)
#define GLD16(gp, lp) __builtin_amdgcn_global_load_lds( \
    (const __attribute__((address_space(1))) unsigned int*)(gp), \
    (__attribute__((address_space(3))) unsigned int*)(lp), 16, 0, 0)

// LDS tiles are [rows][32] f16 (64 B rows, 4x 16B chunks). r12-r14: the
// residual 5.033e7 conflict count in the 32x32-frag kernel is INVARIANT
// under three different read swizzles -> not a read-address effect
// (likely ds_read vs gld_lds-writeback port contention); ~48 cy/wave/step,
// accepted. sigma_gu kept from r14; sigma_dn is the r11-proven one (0).
__device__ __forceinline__ int sigma_gu(int row) {
    return (((row >> 1) & 1) << 1) | ((row >> 2) & 1);
}
__device__ __forceinline__ int swz_gu(int row, int lk) {
    return row * 32 + ((((lk) >> 3) ^ sigma_gu(row)) << 3);
}
__device__ __forceinline__ int sigma_dn(int row) {
    return (row >> 1) & 3;
}
__device__ __forceinline__ int swz_dn(int row, int lk) {
    return row * 32 + ((((lk) >> 3) ^ sigma_dn(row)) << 3);
}

// split fp32 -> hi fp16 + lo fp16 (residual)
__device__ __forceinline__ void cvt8(const float* f, f16x8& h, f16x8& l) {
    #pragma unroll
    for (int j = 0; j < 8; ++j) {
        _Float16 hh = (_Float16)f[j];
        h[j] = hh;
        l[j] = (_Float16)(f[j] - (float)hh);
    }
}

// ---------------------------------------------------------------------------
// Fused prep (1 launch): Wg->gh, Wu->uh, Wd->wdh (fp16), x->xh+xl (split).
// ---------------------------------------------------------------------------
__global__ __launch_bounds__(256) void k_prep(
    const float* __restrict__ Wg, const float* __restrict__ Wu,
    const float* __restrict__ Wd, const float* __restrict__ x,
    _Float16* __restrict__ gh, _Float16* __restrict__ uh,
    _Float16* __restrict__ wdh, _Float16* __restrict__ xh,
    _Float16* __restrict__ xl, int nw8, int nx8)
{
    int i = blockIdx.x * 256 + threadIdx.x;
    const float* s; _Float16* dh; _Float16* dl = nullptr; int j;
    if (i < nw8)            { s = Wg; dh = gh;  j = i; }
    else if (i < 2*nw8)     { s = Wu; dh = uh;  j = i - nw8; }
    else if (i < 3*nw8)     { s = Wd; dh = wdh; j = i - 2*nw8; }
    else if (i < 3*nw8+nx8) { s = x;  dh = xh;  dl = xl; j = i - 3*nw8; }
    else return;
    float4 a = ((const float4*)s)[2*j], b = ((const float4*)s)[2*j+1];
    float f[8] = {a.x,a.y,a.z,a.w,b.x,b.y,b.z,b.w};
    if (dl) {
        f16x8 hh, ll; cvt8(f, hh, ll);
        ((f16x8*)dh)[j] = hh; ((f16x8*)dl)[j] = ll;
    } else {
        f16x8 hh;
        #pragma unroll
        for (int q = 0; q < 8; ++q) hh[q] = (_Float16)f[q];
        ((f16x8*)dh)[j] = hh;
    }
}

// ---------------------------------------------------------------------------
// Up-projection via fp16x2 MFMA on 32x32x16, BIGGER TILE (r14->r15):
// BM=128 tokens, BN=128 ff, BK=32. 4 waves (2x2); per-wave 64 tok x 64 ff
// (g and u). MFMA:overhead ratio doubles vs BN=64 (32 MFMA32 vs 16 per
// wave/K-step; stage 8 GLD16 vs 6; reads 16 vs 12).
// LDS per buf: XH/XL/GH/UH [128][32] = 32KB; x2 = 64KB (2 blk/CU).
// A-frag: row=lane&31, k=(lane>>5)*8+e. C/D: col=lane&31,
// row=(reg&3)+8*(reg>>2)+4*(lane>>5)  [r12-verified via absmax match].
// ---------------------------------------------------------------------------
#define OXH 0
#define OXL (128*32)
#define OGH (2*128*32)
#define OUH (3*128*32)
#define GUBUF (4*128*32)   // 16384 elements = 32KB

__global__ __launch_bounds__(256) void k_gemm_gu_mfma(
    const _Float16* __restrict__ xh, const _Float16* __restrict__ xl,
    const _Float16* __restrict__ gh, const _Float16* __restrict__ uh,
    _Float16* __restrict__ z, int nM)
{
    __shared__ _Float16 L[2 * GUBUF];
    const int t = threadIdx.x, lane = t & 63, wid = t >> 6;

    // 4x4 supertile swizzle for L2 locality (ni now ranges over DF/128=32)
    int bid = blockIdx.x, mi, ni;
    if ((nM & 3) == 0) {
        int st = bid >> 4, lo = bid & 15, nstM = nM >> 2;
        mi = ((st % nstM) << 2) + (lo & 3);
        ni = ((st / nstM) << 2) + (lo >> 2);
    } else { mi = bid % nM; ni = bid / nM; }
    const int m0 = mi * 128, f0 = ni * 128;

    // ---- staging roles (per lane): linear LDS fill, pre-swizzled source ----
    const int rr = lane >> 2, slot = lane & 3;
    size_t xoff[2], goff[2];
    #pragma unroll
    for (int q = 0; q < 2; ++q) {
        int row = wid*32 + q*16 + rr;          // tile row 0..127
        int ss  = slot ^ sigma_gu(row);
        xoff[q] = (size_t)(m0 + row) * (NE*2) + ss*16;
        goff[q] = (size_t)(f0 + row) * (NE*2) + ss*16;
    }
    const char* xhB = (const char*)xh;
    const char* xlB = (const char*)xl;
    const char* ghB = (const char*)gh;
    const char* uhB = (const char*)uh;

    const int wr = wid >> 1, wc = wid & 1;
    const int l31 = lane & 31, lks = (lane >> 5) * 8;   // 32x32 frag coords

    // hoisted, loop-invariant LDS read offsets
    int aoff[2][2], boff[2][2];   // [ksub][tile]
    #pragma unroll
    for (int s = 0; s < 2; ++s) {
        #pragma unroll
        for (int mt = 0; mt < 2; ++mt)
            aoff[s][mt] = swz_gu(wr*64 + mt*32 + l31, s*16 + lks);
        #pragma unroll
        for (int nt = 0; nt < 2; ++nt)
            boff[s][nt] = swz_gu(wc*64 + nt*32 + l31, s*16 + lks);
    }

    f32x16 accg[2][2] = {}, accu[2][2] = {};

    // stage K-step kt into buffer b (8 GLD16/lane)
    #define GU_STAGE(b, kt) do {                                              \
        _Float16* Lb = L + (b) * GUBUF;                                       \
        const size_t ka = (size_t)(kt) * 64;                                  \
        const char* xhK = xhB + ka;  const char* xlK = xlB + ka;              \
        const char* ghK = ghB + ka;  const char* uhK = uhB + ka;              \
        _Pragma("unroll")                                                     \
        for (int q = 0; q < 2; ++q) {                                         \
            GLD16(xhK + xoff[q], Lb + OXH + (wid*32 + q*16)*32);              \
            GLD16(xlK + xoff[q], Lb + OXL + (wid*32 + q*16)*32);              \
            GLD16(ghK + goff[q], Lb + OGH + (wid*32 + q*16)*32);              \
            GLD16(uhK + goff[q], Lb + OUH + (wid*32 + q*16)*32);              \
        }                                                                     \
    } while (0)

    GU_STAGE(0, 0);
    __syncthreads();

    int buf = 0;
    for (int kt = 0; kt < 32; ++kt) {
        if (kt + 1 < 32) GU_STAGE(buf ^ 1, kt + 1);
        const _Float16* Lb = &L[buf * GUBUF];
        #pragma unroll
        for (int s = 0; s < 2; ++s) {
            f16x8 ah[2], al[2], bg[2], bu[2];
            #pragma unroll
            for (int mt = 0; mt < 2; ++mt) {
                ah[mt] = *(const f16x8*)&Lb[OXH + aoff[s][mt]];
                al[mt] = *(const f16x8*)&Lb[OXL + aoff[s][mt]];
            }
            #pragma unroll
            for (int nt = 0; nt < 2; ++nt) {
                bg[nt] = *(const f16x8*)&Lb[OGH + boff[s][nt]];
                bu[nt] = *(const f16x8*)&Lb[OUH + boff[s][nt]];
            }
            #pragma unroll
            for (int nt = 0; nt < 2; ++nt)
                #pragma unroll
                for (int mt = 0; mt < 2; ++mt) {
                    accg[mt][nt] = MFMA32(ah[mt], bg[nt], accg[mt][nt]);
                    accg[mt][nt] = MFMA32(al[mt], bg[nt], accg[mt][nt]);
                    accu[mt][nt] = MFMA32(ah[mt], bu[nt], accu[mt][nt]);
                    accu[mt][nt] = MFMA32(al[mt], bu[nt], accu[mt][nt]);
                }
        }
        __syncthreads();
        buf ^= 1;
    }

    // epilogue: silu(g)*u with native exp; 32x32 C-layout store
    #pragma unroll
    for (int mt = 0; mt < 2; ++mt)
        #pragma unroll
        for (int nt = 0; nt < 2; ++nt)
            #pragma unroll
            for (int r = 0; r < 16; ++r) {
                int row = m0 + wr*64 + mt*32 + (r & 3) + 8*(r >> 2) + 4*(lane >> 5);
                int col = f0 + wc*64 + nt*32 + l31;
                float g = accg[mt][nt][r], u = accu[mt][nt][r];
                float sg = g / (1.0f + __expf(-g));
                z[(size_t)row*DF + col] = (_Float16)(sg * u);
            }
    #undef GU_STAGE
}

// ---------------------------------------------------------------------------
// Exact per-token top-K mask on fp16 z: 2-pass radix select on the 15-bit
// magnitude key; stable ties by ascending index. Masks in place. (r10-verified)
// ---------------------------------------------------------------------------
__global__ __launch_bounds__(256) void k_topk_mask16(_Float16* __restrict__ z)
{
    __shared__ unsigned short zrow[DF];
    __shared__ unsigned hist[256];
    __shared__ int      cnts[256];
    __shared__ unsigned s_b1;
    __shared__ unsigned s_tkey;
    __shared__ int      s_remaining;

    const int t = threadIdx.x;
    unsigned short* zp = (unsigned short*)(z + (size_t)blockIdx.x * DF);

    for (int i = t; i < DF/8; i += 256) {
        ((ushort4*)zrow)[2*i]   = ((const ushort4*)zp)[2*i];
        ((ushort4*)zrow)[2*i+1] = ((const ushort4*)zp)[2*i+1];
    }
    if (t == 0) s_remaining = KACT;
    __syncthreads();

    hist[t] = 0u;
    __syncthreads();
    {
        const int base = t * 16;
        #pragma unroll
        for (int j = 0; j < 16; ++j) {
            unsigned key = zrow[base + j] & 0x7FFFu;
            atomicAdd(&hist[key >> 7], 1u);
        }
    }
    __syncthreads();
    if (t == 0) {
        int rem = s_remaining;
        int b = 255;
        for (; b > 0; --b) {
            int c = (int)hist[b];
            if (rem - c <= 0) break;
            rem -= c;
        }
        s_b1 = (unsigned)b;
        s_remaining = rem;
    }
    __syncthreads();

    const unsigned b1 = s_b1;
    hist[t] = 0u;
    __syncthreads();
    {
        const int base = t * 16;
        #pragma unroll
        for (int j = 0; j < 16; ++j) {
            unsigned key = zrow[base + j] & 0x7FFFu;
            if ((key >> 7) == b1) atomicAdd(&hist[key & 0x7Fu], 1u);
        }
    }
    __syncthreads();
    if (t == 0) {
        int rem = s_remaining;
        int b = 127;
        for (; b > 0; --b) {
            int c = (int)hist[b];
            if (rem - c <= 0) break;
            rem -= c;
        }
        s_tkey = (b1 << 7) | (unsigned)b;
        s_remaining = rem;
    }
    __syncthreads();

    const unsigned tkey = s_tkey;
    const int      E    = s_remaining;

    const int base = t * 16;
    int cnt = 0;
    #pragma unroll
    for (int j = 0; j < 16; ++j)
        if ((zrow[base + j] & 0x7FFFu) == tkey) cnt++;
    cnts[t] = cnt;
    __syncthreads();
    if (t == 0) {
        int run = 0;
        for (int i = 0; i < 256; ++i) { int c = cnts[i]; cnts[i] = run; run += c; }
    }
    __syncthreads();

    int rank = cnts[t];
    #pragma unroll
    for (int q = 0; q < 2; ++q) {
        u16x8 v;
        #pragma unroll
        for (int j = 0; j < 8; ++j) {
            int f = base + q*8 + j;
            unsigned short raw = zrow[f];
            unsigned key = raw & 0x7FFFu;
            bool sel;
            if (key > tkey)       sel = true;
            else if (key == tkey) { sel = (rank < E); rank++; }
            else                  sel = false;
            v[j] = sel ? raw : (unsigned short)0;
        }
        *(u16x8*)(zp + base + q*8) = v;
    }
}

// ---------------------------------------------------------------------------
// Down-projection, single fp16 16x16x32 MFMA, global_load_lds staged.
// (r11-verified structure and sigma_dn — measured 0 conflicts.)
// ---------------------------------------------------------------------------
#define OZH 0
#define OWH (128*32)
#define DNBUF (2*128*32)   // 8192 elements = 16KB

__global__ __launch_bounds__(256) void k_gemm_down_mfma(
    const _Float16* __restrict__ z, const _Float16* __restrict__ wdh,
    float* __restrict__ out, int tok0, int nM)
{
    __shared__ _Float16 L[2 * DNBUF];
    const int t = threadIdx.x, lane = t & 63, wid = t >> 6;

    int bid = blockIdx.x, mi, ni;
    if ((nM & 3) == 0) {
        int st = bid >> 4, lo = bid & 15, nstM = nM >> 2;
        mi = ((st % nstM) << 2) + (lo & 3);
        ni = ((st / nstM) << 2) + (lo >> 2);
    } else { mi = bid % nM; ni = bid / nM; }
    const int m0 = mi * 128, d0 = ni * 128;

    const int rr = lane >> 2, slot = lane & 3;
    size_t zoff[2], wof[2];
    #pragma unroll
    for (int q = 0; q < 2; ++q) {
        int row = wid*32 + q*16 + rr;
        int ss  = slot ^ sigma_dn(row);
        zoff[q] = (size_t)(m0 + row) * (DF*2) + ss*16;
        wof[q]  = (size_t)(d0 + row) * (DF*2) + ss*16;
    }
    const char* zB = (const char*)z;
    const char* wB = (const char*)wdh;

    const int wr = wid >> 1, wc = wid & 1;
    const int lrow = lane & 15, lk = (lane >> 4) * 8;

    int aoff[4], boff[4];
    #pragma unroll
    for (int mf = 0; mf < 4; ++mf)
        aoff[mf] = swz_dn(wr*64 + mf*16 + lrow, lk);
    #pragma unroll
    for (int nf = 0; nf < 4; ++nf)
        boff[nf] = swz_dn(wc*64 + nf*16 + lrow, lk);

    f32x4 acc[4][4] = {};

    #define DN_STAGE(b, kt) do {                                              \
        _Float16* Lb = L + (b) * DNBUF;                                       \
        size_t ka = (size_t)(kt) * 64;                                        \
        _Pragma("unroll")                                                     \
        for (int q = 0; q < 2; ++q) {                                         \
            GLD16(zB + zoff[q] + ka, Lb + OZH + (wid*32 + q*16)*32);          \
            GLD16(wB + wof[q]  + ka, Lb + OWH + (wid*32 + q*16)*32);          \
        }                                                                     \
    } while (0)

    DN_STAGE(0, 0);
    __syncthreads();

    int buf = 0;
    for (int kt = 0; kt < DF/32; ++kt) {
        if (kt + 1 < DF/32) DN_STAGE(buf ^ 1, kt + 1);
        const _Float16* Lb = &L[buf * DNBUF];
        f16x8 ah[4], bh[4];
        #pragma unroll
        for (int mf = 0; mf < 4; ++mf)
            ah[mf] = *(const f16x8*)&Lb[OZH + aoff[mf]];
        #pragma unroll
        for (int nf = 0; nf < 4; ++nf)
            bh[nf] = *(const f16x8*)&Lb[OWH + boff[nf]];
        #pragma unroll
        for (int nf = 0; nf < 4; ++nf)
            #pragma unroll
            for (int mf = 0; mf < 4; ++mf)
                acc[mf][nf] = MFMA16(ah[mf], bh[nf], acc[mf][nf]);
        __syncthreads();
        buf ^= 1;
    }

    #pragma unroll
    for (int mf = 0; mf < 4; ++mf)
        #pragma unroll
        for (int nf = 0; nf < 4; ++nf)
            #pragma unroll
            for (int r = 0; r < 4; ++r) {
                int row = tok0 + m0 + wr*64 + mf*16 + (lane>>4)*4 + r;
                int col = d0 + wc*64 + nf*16 + lrow;
                out[(size_t)row*NE + col] = acc[mf][nf][r];
            }
    #undef DN_STAGE
}

// ---------------------------------------------------------------------------
extern "C" void kernel_launch(void* const* d_in, const int* in_sizes, int n_in,
                              void* d_out, int out_size, void* d_ws, size_t ws_size,
                              hipStream_t stream)
{
    const float* x  = (const float*)d_in[0];
    const float* Wg = (const float*)d_in[1];
    const float* Wu = (const float*)d_in[2];
    const float* Wd = (const float*)d_in[3];
    float* out = (float*)d_out;

    // fixed-size weights: gh/uh (DF*NE f16) + wdh (NE*DF f16) = 3 arrays
    const size_t wElems = (size_t)DF * NE;
    const size_t fixedBytes = wElems * 2 * 3;   // 25 MB

    // chunk tokens: need z fp16 (CT*DF*2) + xh/xl (CT*NE*2 each) + fixed
    int CT = NTOK;
    while (CT > 128 &&
           (size_t)CT*DF*2 + (size_t)CT*NE*4 + fixedBytes > ws_size) CT >>= 1;

    char* wsb = (char*)d_ws;
    _Float16* zbuf = (_Float16*)wsb;
    _Float16* xh   = (_Float16*)(wsb + (size_t)CT*DF*2);
    _Float16* xl   = xh + (size_t)CT*NE;
    _Float16* gh   = xl + (size_t)CT*NE;
    _Float16* uh   = gh + wElems;
    _Float16* wdh  = uh + wElems;

    const int nw8 = (int)(wElems / 8);

    for (int tok0 = 0; tok0 < NTOK; tok0 += CT) {
        int nM  = CT / 128;
        int nx8 = CT * NE / 8;
        int nPrep = 3*nw8 + nx8;
        k_prep<<<dim3((nPrep+255)/256), 256, 0, stream>>>(
            Wg, Wu, Wd, x + (size_t)tok0*NE, gh, uh, wdh, xh, xl, nw8, nx8);
        k_gemm_gu_mfma  <<<dim3(nM * (DF/128)), 256, 0, stream>>>(xh, xl, gh, uh, zbuf, nM);
        k_topk_mask16   <<<dim3(CT),            256, 0, stream>>>(zbuf);
        k_gemm_down_mfma<<<dim3(nM * (NE/128)), 256, 0, stream>>>(zbuf, wdh, out, tok0, nM);
    }
}